// Round 5
// baseline (3134.006 us; speedup 1.0000x reference)
//
#include <hip/hip_runtime.h>
#include <hip/hip_bf16.h>
#include <math.h>

namespace {

constexpr int Bc  = 8;
constexpr int Lc  = 2048;
constexpr int VOC = 1969;
constexpr int VOCP = 2048;            // padded vocab rows for logits GEMM
constexpr int DM  = 768;
constexpr int DI  = 1536;
constexpr int DS  = 16;
constexpr int DC  = 4;
constexpr int DR  = 48;
constexpr int M   = Bc * Lc;          // 16384 rows
constexpr int NC  = 32;               // scan chunks
constexpr int CT  = Lc / NC;          // 64 timesteps per chunk
constexpr float EPS_ = 1e-5f;

typedef __bf16 bf16x8 __attribute__((ext_vector_type(8)));
typedef float  f32x4  __attribute__((ext_vector_type(4)));

__device__ __forceinline__ float siluf(float x) { return x / (1.f + __expf(-x)); }

#define GLOAD16(gp, lp)                                                        \
  __builtin_amdgcn_global_load_lds(                                            \
      (const __attribute__((address_space(1))) void*)(gp),                     \
      (__attribute__((address_space(3))) void*)(lp), 16, 0, 0)

// -------- f32 -> bf16 conversion (packed, no padding) --------
__global__ __launch_bounds__(256) void k_f2b(const float* __restrict__ in,
                                             __bf16* __restrict__ out, int n4) {
  for (int i = blockIdx.x * 256 + threadIdx.x; i < n4; i += gridDim.x * 256) {
    float4 v = *(const float4*)(in + (size_t)i * 4);
    __bf16* o = out + (size_t)i * 4;
    o[0] = (__bf16)v.x; o[1] = (__bf16)v.y; o[2] = (__bf16)v.z; o[3] = (__bf16)v.w;
  }
}

// f32 -> bf16 with per-layer row/col zero-padding.
// out[lay][r][c] (r<rout, c<cout) = (r<rin && c<cin) ? in[lay][r][c] : 0
__global__ __launch_bounds__(256) void k_f2b_pad(const float* __restrict__ in,
                                                 __bf16* __restrict__ out,
                                                 int layers, int rin, int rout,
                                                 int cin, int cout) {
  size_t total = (size_t)layers * rout * cout;
  for (size_t i = (size_t)blockIdx.x * 256 + threadIdx.x; i < total;
       i += (size_t)gridDim.x * 256) {
    int lay = (int)(i / ((size_t)rout * cout));
    int rem = (int)(i % ((size_t)rout * cout));
    int r = rem / cout, c = rem % cout;
    float v = (r < rin && c < cin) ? in[((size_t)lay * rin + r) * cin + c] : 0.f;
    out[i] = (__bf16)v;
  }
}

// h[row,d] = embed[ids[row]][d] + times[row]*time_w[d] + time_b[d]
__global__ void k_embed(const int* __restrict__ ids, const float* __restrict__ times,
                        const float* __restrict__ emb, const float* __restrict__ tw,
                        const float* __restrict__ tb, float* __restrict__ h) {
  int row = blockIdx.x;
  int id  = ids[row];
  float tv = times[row];
  const float* e = emb + (size_t)id * DM;
  for (int d = threadIdx.x; d < DM; d += blockDim.x)
    h[(size_t)row * DM + d] = e[d] + tv * tw[d] + tb[d];
}

// bf16 out: o[row,:] = x[row,:] * rsqrt(mean(x^2)+eps) * w
__global__ __launch_bounds__(256) void k_rmsnorm(const float* __restrict__ x,
                                                 const float* __restrict__ w,
                                                 __bf16* __restrict__ o) {
  int row = blockIdx.x;
  const float* xr = x + (size_t)row * DM;
  float v[3];
  float s = 0.f;
#pragma unroll
  for (int i = 0; i < 3; i++) { v[i] = xr[threadIdx.x + 256 * i]; s += v[i] * v[i]; }
#pragma unroll
  for (int off = 32; off > 0; off >>= 1) s += __shfl_down(s, off);
  __shared__ float red[4];
  int lane = threadIdx.x & 63, wv = threadIdx.x >> 6;
  if (lane == 0) red[wv] = s;
  __syncthreads();
  if (threadIdx.x == 0)
    red[0] = rsqrtf((red[0] + red[1] + red[2] + red[3]) / (float)DM + EPS_);
  __syncthreads();
  float sc = red[0];
#pragma unroll
  for (int i = 0; i < 3; i++) {
    int d = threadIdx.x + 256 * i;
    o[(size_t)row * DM + d] = (__bf16)(v[i] * sc * w[d]);
  }
}

// Depthwise causal conv (width 4) + bias + silu ; bf16 in (dense [M][DI]) / bf16 out.
__global__ __launch_bounds__(256) void k_conv(const __bf16* __restrict__ xb,
                                              const float* __restrict__ cwt,
                                              const float* __restrict__ cbv,
                                              __bf16* __restrict__ xo) {
  size_t idx = (size_t)blockIdx.x * blockDim.x + threadIdx.x;
  if (idx >= (size_t)M * DI) return;
  int d = (int)(idx % DI);
  size_t row = idx / DI;
  int t = (int)(row % Lc);
  size_t b = row / Lc;
  float acc = cbv[d];
#pragma unroll
  for (int j = 0; j < DC; j++) {
    int tt = t - (DC - 1) + j;
    if (tt >= 0) acc += cwt[d * DC + j] * (float)xb[((size_t)b * Lc + tt) * DI + d];
  }
  xo[idx] = (__bf16)siluf(acc);
}

// ---------------- bf16 MFMA GEMM (m97 structure) ----------------
// C[M x N] (+)= act(A[M x K(lda)] * W[N x K(ldw)]^T + bias)
// 128x128 tile, BK=32, 256 threads = 4 waves (2x2), 64x64 per wave.
// Staging: global_load_lds width=16, LINEAR LDS dest (wave-uniform base + lane*16),
// K-chunk slot rotation f(r)=r+(r>>2) applied to the per-lane GLOBAL source and to
// the ds_read address (rule 21: both-sides bijection) -> ~2-way read conflicts.
// All N-rows of W must exist (caller zero-pads weights); M % 128 == 0.
__global__ __launch_bounds__(256) void k_gemm_mfma(
    const __bf16* __restrict__ A, int lda,
    const __bf16* __restrict__ W, int ldw,
    const float* __restrict__ bias,
    float* __restrict__ Cf, __bf16* __restrict__ Cb, int ldc,
    int N, int K, int act, int resAdd) {
  __shared__ __bf16 As[128 * 32];
  __shared__ __bf16 Bs[128 * 32];
  int tid = threadIdx.x;
  int l = tid & 63, w = tid >> 6;
  int wr = w >> 1, wc = w & 1;
  int bm = blockIdx.x << 7, bn = blockIdx.y << 7;

  // --- staging addresses: wave w stages rows [32w,32w+32) of both tiles ---
  int lrow = l >> 2, lslot = l & 3;
  int r0 = w * 32 + lrow;            // rows r0 and r0+16
  int r1 = r0 + 16;
  int sg0 = (lslot - r0 - (r0 >> 2)) & 3;   // pre-permuted source slot
  int sg1 = (lslot - r1 - (r1 >> 2)) & 3;
  const char* gA0 = (const char*)(A + (size_t)(bm + r0) * lda) + sg0 * 16;
  const char* gA1 = (const char*)(A + (size_t)(bm + r1) * lda) + sg1 * 16;
  const char* gB0 = (const char*)(W + (size_t)(bn + r0) * ldw) + sg0 * 16;
  const char* gB1 = (const char*)(W + (size_t)(bn + r1) * ldw) + sg1 * 16;
  __bf16* lA0 = As + (w * 32) * 32;         // wave-uniform LDS bases (elements)
  __bf16* lA1 = As + (w * 32 + 16) * 32;
  __bf16* lB0 = Bs + (w * 32) * 32;
  __bf16* lB1 = Bs + (w * 32 + 16) * 32;

  // --- fragment read offsets (elements), constant across K-steps ---
  int aoff[4], boff[4];
#pragma unroll
  for (int i = 0; i < 4; i++) {
    int ra = wr * 64 + i * 16 + (l & 15);
    aoff[i] = ra * 32 + ((((l >> 4) + ra + (ra >> 2)) & 3) << 3);
    int rb = wc * 64 + i * 16 + (l & 15);
    boff[i] = rb * 32 + ((((l >> 4) + rb + (rb >> 2)) & 3) << 3);
  }

  f32x4 acc[4][4];
#pragma unroll
  for (int i = 0; i < 4; i++)
#pragma unroll
    for (int j = 0; j < 4; j++)
#pragma unroll
      for (int e = 0; e < 4; e++) acc[i][j][e] = 0.f;

  for (int k0 = 0; k0 < K; k0 += 32) {
    size_t kb = (size_t)k0 * 2;
    __syncthreads();                  // previous tile fully consumed
    GLOAD16(gA0 + kb, lA0);
    GLOAD16(gA1 + kb, lA1);
    GLOAD16(gB0 + kb, lB0);
    GLOAD16(gB1 + kb, lB1);
    __syncthreads();                  // compiler drains vmcnt before barrier
    bf16x8 af[4], bfr[4];
#pragma unroll
    for (int i = 0; i < 4; i++) {
      af[i]  = *(const bf16x8*)(As + aoff[i]);
      bfr[i] = *(const bf16x8*)(Bs + boff[i]);
    }
#pragma unroll
    for (int i = 0; i < 4; i++)
#pragma unroll
      for (int j = 0; j < 4; j++)
        acc[i][j] = __builtin_amdgcn_mfma_f32_16x16x32_bf16(af[i], bfr[j], acc[i][j], 0, 0, 0);
  }

#pragma unroll
  for (int i = 0; i < 4; i++) {
#pragma unroll
    for (int r = 0; r < 4; r++) {
      int grow = bm + wr * 64 + i * 16 + (l >> 4) * 4 + r;
#pragma unroll
      for (int j = 0; j < 4; j++) {
        int gcol = bn + wc * 64 + j * 16 + (l & 15);
        if (gcol < N) {
          float v = acc[i][j][r];
          if (bias) v += bias[gcol];
          if (act == 1) v = (v > 20.f) ? v : log1pf(__expf(v));  // softplus
          size_t off = (size_t)grow * ldc + gcol;
          if (Cb) Cb[off] = (__bf16)v;
          else if (resAdd) Cf[off] += v;
          else Cf[off] = v;
        }
      }
    }
  }
}

// ---------------- chunked selective scan ----------------
// delta: dense f32 [M][DI]; u: bf16 [M][DI]; B/C: bf16 xdbl [M][80]; z: bf16 [M][DI].
__global__ __launch_bounds__(256) void k_scan1(
    const float* __restrict__ dlt,
    const __bf16* __restrict__ u_xc,
    const __bf16* __restrict__ xdbl,
    const float* __restrict__ alog,
    float* __restrict__ sc) {
  __shared__ float bcs[CT][32];
  int b = blockIdx.z, c = blockIdx.y;
  int d = blockIdx.x * 256 + threadIdx.x;
  int row0 = b * Lc + c * CT;
#pragma unroll
  for (int k = 0; k < (CT * 32) / 256; k++) {
    int i = k * 256 + threadIdx.x;
    int t = i >> 5, j = i & 31;
    bcs[t][j] = (float)xdbl[(size_t)(row0 + t) * 80 + 48 + j];
  }
  float Av[16];
#pragma unroll
  for (int n = 0; n < 16; n++) Av[n] = -__expf(alog[d * DS + n]);
  float h[16], P[16];
#pragma unroll
  for (int n = 0; n < 16; n++) { h[n] = 0.f; P[n] = 1.f; }
  __syncthreads();
  for (int t = 0; t < CT; t++) {
    size_t row = row0 + t;
    float dl = dlt[row * DI + d];
    float u  = (float)u_xc[row * DI + d];
    float du = dl * u;
#pragma unroll
    for (int n = 0; n < 16; n++) {
      float e = __expf(dl * Av[n]);
      h[n] = h[n] * e + du * bcs[t][n];
      P[n] *= e;
    }
  }
  float* o = sc + (((size_t)b * NC + c) * DI + d) * 32;
#pragma unroll
  for (int n = 0; n < 16; n += 4) {
    *(float4*)(o + n)      = make_float4(h[n], h[n + 1], h[n + 2], h[n + 3]);
    *(float4*)(o + 16 + n) = make_float4(P[n], P[n + 1], P[n + 2], P[n + 3]);
  }
}

__global__ __launch_bounds__(256) void k_scan2(float* __restrict__ sc) {
  int g = blockIdx.x * 256 + threadIdx.x;
  int n = g & 15;
  int rest = g >> 4;
  int d = rest % DI;
  int b = rest / DI;
  float cur = 0.f;
  for (int c = 0; c < NC; c++) {
    float* p = sc + (((size_t)b * NC + c) * DI + d) * 32;
    float hf = p[n];
    float pd = p[16 + n];
    p[n] = cur;
    cur = pd * cur + hf;
  }
}

__global__ __launch_bounds__(256) void k_scan3(
    const float* __restrict__ dlt,
    const __bf16* __restrict__ zb,
    __bf16* __restrict__ u_xc,          // in: u, out: y*silu(z)
    const __bf16* __restrict__ xdbl,
    const float* __restrict__ alog,
    const float* __restrict__ dsk,
    const float* __restrict__ sc) {
  __shared__ float bcs[CT][32];
  int b = blockIdx.z, c = blockIdx.y;
  int d = blockIdx.x * 256 + threadIdx.x;
  int row0 = b * Lc + c * CT;
#pragma unroll
  for (int k = 0; k < (CT * 32) / 256; k++) {
    int i = k * 256 + threadIdx.x;
    int t = i >> 5, j = i & 31;
    bcs[t][j] = (float)xdbl[(size_t)(row0 + t) * 80 + 48 + j];
  }
  float Av[16];
#pragma unroll
  for (int n = 0; n < 16; n++) Av[n] = -__expf(alog[d * DS + n]);
  float Dv = dsk[d];
  float h[16];
  const float* ip = sc + (((size_t)b * NC + c) * DI + d) * 32;
#pragma unroll
  for (int n = 0; n < 16; n += 4) {
    float4 v = *(const float4*)(ip + n);
    h[n] = v.x; h[n + 1] = v.y; h[n + 2] = v.z; h[n + 3] = v.w;
  }
  __syncthreads();
  for (int t = 0; t < CT; t++) {
    size_t row = row0 + t;
    float dl = dlt[row * DI + d];
    float u  = (float)u_xc[row * DI + d];
    float du = dl * u;
    float y = 0.f;
#pragma unroll
    for (int n = 0; n < 16; n++) {
      float e = __expf(dl * Av[n]);
      h[n] = h[n] * e + du * bcs[t][n];
      y += h[n] * bcs[t][16 + n];
    }
    y += u * Dv;
    float z = (float)zb[row * DI + d];
    u_xc[row * DI + d] = (__bf16)(y * siluf(z));
  }
}

}  // namespace

extern "C" void kernel_launch(void* const* d_in, const int* in_sizes, int n_in,
                              void* d_out, int out_size, void* d_ws, size_t ws_size,
                              hipStream_t stream) {
  const int*   ids   = (const int*)d_in[0];
  const float* times = (const float*)d_in[1];
  const float* emb   = (const float*)d_in[3];
  const float* tw    = (const float*)d_in[4];
  const float* tb    = (const float*)d_in[5];
  const float* inw   = (const float*)d_in[6];
  const float* cw    = (const float*)d_in[7];
  const float* cb    = (const float*)d_in[8];
  const float* xw    = (const float*)d_in[9];
  const float* dtw   = (const float*)d_in[10];
  const float* dtb   = (const float*)d_in[11];
  const float* alog  = (const float*)d_in[12];
  const float* dsk   = (const float*)d_in[13];
  const float* ow    = (const float*)d_in[14];
  const float* nw    = (const float*)d_in[15];
  const float* nfw   = (const float*)d_in[16];
  float* out = (float*)d_out;

  // ---- workspace layout (f32 first, then bf16; all 16B aligned) ----
  float* wsf  = (float*)d_ws;
  float* h    = wsf;  wsf += (size_t)M * DM;                 // 50.3 MB
  float* dlt  = wsf;  wsf += (size_t)M * DI;                 // 100.7 MB
  float* scb  = wsf;  wsf += (size_t)Bc * NC * DI * 32;      // 50.3 MB
  __bf16* wsb = (__bf16*)wsf;
  __bf16* hnb   = wsb;  wsb += (size_t)M * DM;               // 25.2 MB
  __bf16* xb    = wsb;  wsb += (size_t)M * DI;               // 50.3 MB
  __bf16* zbuf  = wsb;  wsb += (size_t)M * DI;               // 50.3 MB
  __bf16* xcb   = wsb;  wsb += (size_t)M * DI;               // 50.3 MB
  __bf16* xdblb = wsb;  wsb += (size_t)M * 80;               // 2.6 MB
  __bf16* ebw   = wsb;  wsb += (size_t)VOCP * DM;            // 3.1 MB (rows padded)
  __bf16* inwb  = wsb;  wsb += (size_t)4 * 2 * DI * DM;      // 18.9 MB
  __bf16* xwb   = wsb;  wsb += (size_t)4 * 128 * DI;         // 1.6 MB (80->128 rows)
  __bf16* owb   = wsb;  wsb += (size_t)4 * DM * DI;          // 9.4 MB
  __bf16* dtwb  = wsb;  wsb += (size_t)4 * DI * 64;          // 0.8 MB (48->64 cols)

  // weight / embed conversions (every call; deterministic)
  k_f2b<<<2048, 256, 0, stream>>>(inw, inwb, (4 * 2 * DI * DM) / 4);
  k_f2b<<<2048, 256, 0, stream>>>(ow,  owb,  (4 * DM * DI) / 4);
  k_f2b_pad<<<2048, 256, 0, stream>>>(emb, ebw, 1, VOC, VOCP, DM, DM);
  k_f2b_pad<<<1024, 256, 0, stream>>>(xw,  xwb, 4, 80, 128, DI, DI);
  k_f2b_pad<<<1024, 256, 0, stream>>>(dtw, dtwb, 4, DI, DI, DR, 64);

  k_embed<<<M, 256, 0, stream>>>(ids, times, emb, tw, tb, h);

  for (int i = 0; i < 4; i++) {
    k_rmsnorm<<<M, 256, 0, stream>>>(h, nw + i * DM, hnb);
    {  // x = hn @ in_proj_x^T ; z = hn @ in_proj_z^T   (bf16 out)
      dim3 g(M / 128, DI / 128);
      k_gemm_mfma<<<g, 256, 0, stream>>>(hnb, DM, inwb + (size_t)i * 2 * DI * DM, DM,
                                         nullptr, nullptr, xb, DI, DI, DM, 0, 0);
      k_gemm_mfma<<<g, 256, 0, stream>>>(hnb, DM,
                                         inwb + (size_t)i * 2 * DI * DM + (size_t)DI * DM, DM,
                                         nullptr, nullptr, zbuf, DI, DI, DM, 0, 0);
    }
    {  // xcb = silu(conv1d(x) + cb)
      size_t n = (size_t)M * DI;
      k_conv<<<(int)((n + 255) / 256), 256, 0, stream>>>(xb, cw + i * DI * DC,
                                                         cb + i * DI, xcb);
    }
    {  // xdbl = xc @ x_proj^T  (bf16 out, N=80, padded weights)
      dim3 g(M / 128, 1);
      k_gemm_mfma<<<g, 256, 0, stream>>>(xcb, DI, xwb + (size_t)i * 128 * DI, DI,
                                         nullptr, nullptr, xdblb, 80, 80, DI, 0, 0);
    }
    {  // delta = softplus(xdbl[:, :64pad] @ dtw_pad^T + dtb)  (f32 out)
      dim3 g(M / 128, DI / 128);
      k_gemm_mfma<<<g, 256, 0, stream>>>(xdblb, 80, dtwb + (size_t)i * DI * 64, 64,
                                         dtb + i * DI, dlt, nullptr, DI, DI, 64, 1, 0);
    }
    {  // chunked selective scan + y*silu(z), in place over xcb
      dim3 g1(DI / 256, NC, Bc);
      k_scan1<<<g1, 256, 0, stream>>>(dlt, xcb, xdblb, alog + (size_t)i * DI * DS, scb);
      k_scan2<<<(Bc * DI * DS) / 256, 256, 0, stream>>>(scb);
      k_scan3<<<g1, 256, 0, stream>>>(dlt, zbuf, xcb, xdblb,
                                      alog + (size_t)i * DI * DS, dsk + i * DI, scb);
    }
    {  // h += y @ out_proj^T   (f32, resAdd)
      dim3 g(M / 128, DM / 128);
      k_gemm_mfma<<<g, 256, 0, stream>>>(xcb, DI, owb + (size_t)i * DM * DI, DI,
                                         nullptr, h, nullptr, DM, DM, DI, 0, 1);
    }
  }

  k_rmsnorm<<<M, 256, 0, stream>>>(h, nfw, hnb);
  {  // logits = hn @ embed^T   (N=1969, padded rows)
    dim3 g(M / 128, VOCP / 128);
    k_gemm_mfma<<<g, 256, 0, stream>>>(hnb, DM, ebw, DM,
                                       nullptr, out, nullptr, VOC, VOC, DM, 0, 0);
  }
}

// Round 6
// 2858.897 us; speedup vs baseline: 1.0962x; 1.0962x over previous
//
#include <hip/hip_runtime.h>
#include <hip/hip_bf16.h>
#include <math.h>

namespace {

constexpr int Bc  = 8;
constexpr int Lc  = 2048;
constexpr int VOC = 1969;
constexpr int VOCP = 2048;            // padded vocab rows for logits GEMM
constexpr int DM  = 768;
constexpr int DI  = 1536;
constexpr int DS  = 16;
constexpr int DC  = 4;
constexpr int DR  = 48;
constexpr int M   = Bc * Lc;          // 16384 rows
constexpr int NC  = 32;               // scan chunks
constexpr int CT  = Lc / NC;          // 64 timesteps per chunk
constexpr float EPS_ = 1e-5f;

typedef __bf16 bf16x8 __attribute__((ext_vector_type(8)));
typedef float  f32x4  __attribute__((ext_vector_type(4)));

__device__ __forceinline__ float siluf(float x) { return x / (1.f + __expf(-x)); }
// fast softplus: 2 HW transcendentals (v_exp_f32 + v_log_f32), ~1e-5 rel err
__device__ __forceinline__ float softplusf(float x) {
  return (x > 20.f) ? x : __logf(1.f + __expf(x));
}

#define GLOAD16(gp, lp)                                                        \
  __builtin_amdgcn_global_load_lds(                                            \
      (const __attribute__((address_space(1))) void*)(gp),                     \
      (__attribute__((address_space(3))) void*)(lp), 16, 0, 0)

// -------- f32 -> bf16 conversion (packed, no padding) --------
__global__ __launch_bounds__(256) void k_f2b(const float* __restrict__ in,
                                             __bf16* __restrict__ out, int n4) {
  for (int i = blockIdx.x * 256 + threadIdx.x; i < n4; i += gridDim.x * 256) {
    float4 v = *(const float4*)(in + (size_t)i * 4);
    __bf16* o = out + (size_t)i * 4;
    o[0] = (__bf16)v.x; o[1] = (__bf16)v.y; o[2] = (__bf16)v.z; o[3] = (__bf16)v.w;
  }
}

// f32 -> bf16 with per-layer row/col zero-padding.
__global__ __launch_bounds__(256) void k_f2b_pad(const float* __restrict__ in,
                                                 __bf16* __restrict__ out,
                                                 int layers, int rin, int rout,
                                                 int cin, int cout) {
  size_t total = (size_t)layers * rout * cout;
  for (size_t i = (size_t)blockIdx.x * 256 + threadIdx.x; i < total;
       i += (size_t)gridDim.x * 256) {
    int lay = (int)(i / ((size_t)rout * cout));
    int rem = (int)(i % ((size_t)rout * cout));
    int r = rem / cout, c = rem % cout;
    float v = (r < rin && c < cin) ? in[((size_t)lay * rin + r) * cin + c] : 0.f;
    out[i] = (__bf16)v;
  }
}

// h[row,d] = embed[ids[row]][d] + times[row]*time_w[d] + time_b[d]
__global__ void k_embed(const int* __restrict__ ids, const float* __restrict__ times,
                        const float* __restrict__ emb, const float* __restrict__ tw,
                        const float* __restrict__ tb, float* __restrict__ h) {
  int row = blockIdx.x;
  int id  = ids[row];
  float tv = times[row];
  const float* e = emb + (size_t)id * DM;
  for (int d = threadIdx.x; d < DM; d += blockDim.x)
    h[(size_t)row * DM + d] = e[d] + tv * tw[d] + tb[d];
}

// bf16 out: o[row,:] = x[row,:] * rsqrt(mean(x^2)+eps) * w
__global__ __launch_bounds__(256) void k_rmsnorm(const float* __restrict__ x,
                                                 const float* __restrict__ w,
                                                 __bf16* __restrict__ o) {
  int row = blockIdx.x;
  const float* xr = x + (size_t)row * DM;
  float v[3];
  float s = 0.f;
#pragma unroll
  for (int i = 0; i < 3; i++) { v[i] = xr[threadIdx.x + 256 * i]; s += v[i] * v[i]; }
#pragma unroll
  for (int off = 32; off > 0; off >>= 1) s += __shfl_down(s, off);
  __shared__ float red[4];
  int lane = threadIdx.x & 63, wv = threadIdx.x >> 6;
  if (lane == 0) red[wv] = s;
  __syncthreads();
  if (threadIdx.x == 0)
    red[0] = rsqrtf((red[0] + red[1] + red[2] + red[3]) / (float)DM + EPS_);
  __syncthreads();
  float sc = red[0];
#pragma unroll
  for (int i = 0; i < 3; i++) {
    int d = threadIdx.x + 256 * i;
    o[(size_t)row * DM + d] = (__bf16)(v[i] * sc * w[d]);
  }
}

// Depthwise causal conv (width 4) + bias + silu ; bf16x8 vectorized.
// One thread per 8 consecutive d's.
__global__ __launch_bounds__(256) void k_conv8(const __bf16* __restrict__ xb,
                                               const float* __restrict__ cwt,
                                               const float* __restrict__ cbv,
                                               __bf16* __restrict__ xo) {
  size_t idx = (size_t)blockIdx.x * 256 + threadIdx.x;   // < M*DI/8
  int dg = (int)(idx % (DI / 8));
  size_t row = idx / (DI / 8);
  int d0 = dg * 8;
  int t = (int)(row % Lc);
  size_t b = row / Lc;
  float acc[8];
  float4 cwv[8];
#pragma unroll
  for (int j = 0; j < 8; j++) {
    acc[j] = cbv[d0 + j];
    cwv[j] = *(const float4*)(cwt + (d0 + j) * DC);
  }
#pragma unroll
  for (int tap = 0; tap < DC; tap++) {
    int tt = t - (DC - 1) + tap;
    if (tt >= 0) {
      bf16x8 v = *(const bf16x8*)(xb + ((size_t)b * Lc + tt) * DI + d0);
#pragma unroll
      for (int j = 0; j < 8; j++) {
        float wt = (tap == 0) ? cwv[j].x : (tap == 1) ? cwv[j].y
                   : (tap == 2) ? cwv[j].z : cwv[j].w;
        acc[j] += wt * (float)v[j];
      }
    }
  }
  bf16x8 o;
#pragma unroll
  for (int j = 0; j < 8; j++) o[j] = (__bf16)siluf(acc[j]);
  *(bf16x8*)(xo + idx * 8) = o;
}

// ---------------- bf16 MFMA GEMM (m97 structure) ----------------
// C[M x N] (+)= act(A[M x K(lda)] * W[N x K(ldw)]^T + bias)
// 128x128 tile, BK=32, 256 threads = 4 waves (2x2), 64x64 per wave.
__global__ __launch_bounds__(256) void k_gemm_mfma(
    const __bf16* __restrict__ A, int lda,
    const __bf16* __restrict__ W, int ldw,
    const float* __restrict__ bias,
    float* __restrict__ Cf, __bf16* __restrict__ Cb, int ldc,
    int N, int K, int act, int resAdd) {
  __shared__ __bf16 As[128 * 32];
  __shared__ __bf16 Bs[128 * 32];
  int tid = threadIdx.x;
  int l = tid & 63, w = tid >> 6;
  int wr = w >> 1, wc = w & 1;
  int bm = blockIdx.x << 7, bn = blockIdx.y << 7;

  // --- staging: wave w stages rows [32w,32w+32) of both tiles ---
  int lrow = l >> 2, lslot = l & 3;
  int r0 = w * 32 + lrow;
  int r1 = r0 + 16;
  int sg0 = (lslot - r0 - (r0 >> 2)) & 3;   // pre-permuted source slot
  int sg1 = (lslot - r1 - (r1 >> 2)) & 3;
  const char* gA0 = (const char*)(A + (size_t)(bm + r0) * lda) + sg0 * 16;
  const char* gA1 = (const char*)(A + (size_t)(bm + r1) * lda) + sg1 * 16;
  const char* gB0 = (const char*)(W + (size_t)(bn + r0) * ldw) + sg0 * 16;
  const char* gB1 = (const char*)(W + (size_t)(bn + r1) * ldw) + sg1 * 16;
  __bf16* lA0 = As + (w * 32) * 32;
  __bf16* lA1 = As + (w * 32 + 16) * 32;
  __bf16* lB0 = Bs + (w * 32) * 32;
  __bf16* lB1 = Bs + (w * 32 + 16) * 32;

  // --- fragment read offsets (elements) ---
  int aoff[4], boff[4];
#pragma unroll
  for (int i = 0; i < 4; i++) {
    int ra = wr * 64 + i * 16 + (l & 15);
    aoff[i] = ra * 32 + ((((l >> 4) + ra + (ra >> 2)) & 3) << 3);
    int rb = wc * 64 + i * 16 + (l & 15);
    boff[i] = rb * 32 + ((((l >> 4) + rb + (rb >> 2)) & 3) << 3);
  }

  f32x4 acc[4][4];
#pragma unroll
  for (int i = 0; i < 4; i++)
#pragma unroll
    for (int j = 0; j < 4; j++)
#pragma unroll
      for (int e = 0; e < 4; e++) acc[i][j][e] = 0.f;

  for (int k0 = 0; k0 < K; k0 += 32) {
    size_t kb = (size_t)k0 * 2;
    __syncthreads();
    GLOAD16(gA0 + kb, lA0);
    GLOAD16(gA1 + kb, lA1);
    GLOAD16(gB0 + kb, lB0);
    GLOAD16(gB1 + kb, lB1);
    __syncthreads();
    bf16x8 af[4], bfr[4];
#pragma unroll
    for (int i = 0; i < 4; i++) {
      af[i]  = *(const bf16x8*)(As + aoff[i]);
      bfr[i] = *(const bf16x8*)(Bs + boff[i]);
    }
#pragma unroll
    for (int i = 0; i < 4; i++)
#pragma unroll
      for (int j = 0; j < 4; j++)
        acc[i][j] = __builtin_amdgcn_mfma_f32_16x16x32_bf16(af[i], bfr[j], acc[i][j], 0, 0, 0);
  }

#pragma unroll
  for (int i = 0; i < 4; i++) {
#pragma unroll
    for (int r = 0; r < 4; r++) {
      int grow = bm + wr * 64 + i * 16 + (l >> 4) * 4 + r;
#pragma unroll
      for (int j = 0; j < 4; j++) {
        int gcol = bn + wc * 64 + j * 16 + (l & 15);
        if (gcol < N) {
          float v = acc[i][j][r];
          if (bias) v += bias[gcol];
          if (act == 1) v = softplusf(v);
          size_t off = (size_t)grow * ldc + gcol;
          if (Cb) Cb[off] = (__bf16)v;
          else if (resAdd) Cf[off] += v;
          else Cf[off] = v;
        }
      }
    }
  }
}

// ---------------- chunked selective scan ----------------
// delta: bf16 [M][DI]; u: bf16 [M][DI]; B/C: bf16 xdbl [M][80]; z: bf16 [M][DI].
__global__ __launch_bounds__(256) void k_scan1(
    const __bf16* __restrict__ dlt,
    const __bf16* __restrict__ u_xc,
    const __bf16* __restrict__ xdbl,
    const float* __restrict__ alog,
    float* __restrict__ sc) {
  __shared__ float bcs[CT][32];
  int b = blockIdx.z, c = blockIdx.y;
  int d = blockIdx.x * 256 + threadIdx.x;
  int row0 = b * Lc + c * CT;
#pragma unroll
  for (int k = 0; k < (CT * 32) / 256; k++) {
    int i = k * 256 + threadIdx.x;
    int t = i >> 5, j = i & 31;
    bcs[t][j] = (float)xdbl[(size_t)(row0 + t) * 80 + 48 + j];
  }
  float Av[16];
#pragma unroll
  for (int n = 0; n < 16; n++) Av[n] = -__expf(alog[d * DS + n]);
  float h[16], P[16];
#pragma unroll
  for (int n = 0; n < 16; n++) { h[n] = 0.f; P[n] = 1.f; }
  __syncthreads();
  for (int t = 0; t < CT; t++) {
    size_t row = row0 + t;
    float dl = (float)dlt[row * DI + d];
    float u  = (float)u_xc[row * DI + d];
    float du = dl * u;
#pragma unroll
    for (int n = 0; n < 16; n++) {
      float e = __expf(dl * Av[n]);
      h[n] = h[n] * e + du * bcs[t][n];
      P[n] *= e;
    }
  }
  float* o = sc + (((size_t)b * NC + c) * DI + d) * 32;
#pragma unroll
  for (int n = 0; n < 16; n += 4) {
    *(float4*)(o + n)      = make_float4(h[n], h[n + 1], h[n + 2], h[n + 3]);
    *(float4*)(o + 16 + n) = make_float4(P[n], P[n + 1], P[n + 2], P[n + 3]);
  }
}

__global__ __launch_bounds__(256) void k_scan2(float* __restrict__ sc) {
  int g = blockIdx.x * 256 + threadIdx.x;
  int n = g & 15;
  int rest = g >> 4;
  int d = rest % DI;
  int b = rest / DI;
  float cur = 0.f;
  for (int c = 0; c < NC; c++) {
    float* p = sc + (((size_t)b * NC + c) * DI + d) * 32;
    float hf = p[n];
    float pd = p[16 + n];
    p[n] = cur;
    cur = pd * cur + hf;
  }
}

__global__ __launch_bounds__(256) void k_scan3(
    const __bf16* __restrict__ dlt,
    const __bf16* __restrict__ zb,
    __bf16* __restrict__ u_xc,          // in: u, out: y*silu(z)
    const __bf16* __restrict__ xdbl,
    const float* __restrict__ alog,
    const float* __restrict__ dsk,
    const float* __restrict__ sc) {
  __shared__ float bcs[CT][32];
  int b = blockIdx.z, c = blockIdx.y;
  int d = blockIdx.x * 256 + threadIdx.x;
  int row0 = b * Lc + c * CT;
#pragma unroll
  for (int k = 0; k < (CT * 32) / 256; k++) {
    int i = k * 256 + threadIdx.x;
    int t = i >> 5, j = i & 31;
    bcs[t][j] = (float)xdbl[(size_t)(row0 + t) * 80 + 48 + j];
  }
  float Av[16];
#pragma unroll
  for (int n = 0; n < 16; n++) Av[n] = -__expf(alog[d * DS + n]);
  float Dv = dsk[d];
  float h[16];
  const float* ip = sc + (((size_t)b * NC + c) * DI + d) * 32;
#pragma unroll
  for (int n = 0; n < 16; n += 4) {
    float4 v = *(const float4*)(ip + n);
    h[n] = v.x; h[n + 1] = v.y; h[n + 2] = v.z; h[n + 3] = v.w;
  }
  __syncthreads();
  for (int t = 0; t < CT; t++) {
    size_t row = row0 + t;
    float dl = (float)dlt[row * DI + d];
    float u  = (float)u_xc[row * DI + d];
    float du = dl * u;
    float y = 0.f;
#pragma unroll
    for (int n = 0; n < 16; n++) {
      float e = __expf(dl * Av[n]);
      h[n] = h[n] * e + du * bcs[t][n];
      y += h[n] * bcs[t][16 + n];
    }
    y += u * Dv;
    float z = (float)zb[row * DI + d];
    u_xc[row * DI + d] = (__bf16)(y * siluf(z));
  }
}

}  // namespace

extern "C" void kernel_launch(void* const* d_in, const int* in_sizes, int n_in,
                              void* d_out, int out_size, void* d_ws, size_t ws_size,
                              hipStream_t stream) {
  const int*   ids   = (const int*)d_in[0];
  const float* times = (const float*)d_in[1];
  const float* emb   = (const float*)d_in[3];
  const float* tw    = (const float*)d_in[4];
  const float* tb    = (const float*)d_in[5];
  const float* inw   = (const float*)d_in[6];
  const float* cw    = (const float*)d_in[7];
  const float* cb    = (const float*)d_in[8];
  const float* xw    = (const float*)d_in[9];
  const float* dtw   = (const float*)d_in[10];
  const float* dtb   = (const float*)d_in[11];
  const float* alog  = (const float*)d_in[12];
  const float* dsk   = (const float*)d_in[13];
  const float* ow    = (const float*)d_in[14];
  const float* nw    = (const float*)d_in[15];
  const float* nfw   = (const float*)d_in[16];
  float* out = (float*)d_out;

  // ---- workspace layout (f32 first, then bf16; all 16B aligned) ----
  float* wsf  = (float*)d_ws;
  float* h    = wsf;  wsf += (size_t)M * DM;                 // 50.3 MB
  float* scb  = wsf;  wsf += (size_t)Bc * NC * DI * 32;      // 50.3 MB
  __bf16* wsb = (__bf16*)wsf;
  __bf16* hnb   = wsb;  wsb += (size_t)M * DM;               // 25.2 MB
  __bf16* xb    = wsb;  wsb += (size_t)M * DI;               // 50.3 MB
  __bf16* zbuf  = wsb;  wsb += (size_t)M * DI;               // 50.3 MB
  __bf16* xcb   = wsb;  wsb += (size_t)M * DI;               // 50.3 MB
  __bf16* dltb  = wsb;  wsb += (size_t)M * DI;               // 50.3 MB (bf16 delta)
  __bf16* xdblb = wsb;  wsb += (size_t)M * 80;               // 2.6 MB
  __bf16* ebw   = wsb;  wsb += (size_t)VOCP * DM;            // 3.1 MB
  __bf16* inwb  = wsb;  wsb += (size_t)4 * 2 * DI * DM;      // 18.9 MB
  __bf16* xwb   = wsb;  wsb += (size_t)4 * 128 * DI;         // 1.6 MB
  __bf16* owb   = wsb;  wsb += (size_t)4 * DM * DI;          // 9.4 MB
  __bf16* dtwb  = wsb;  wsb += (size_t)4 * DI * 64;          // 0.8 MB

  // weight / embed conversions (every call; deterministic)
  k_f2b<<<2048, 256, 0, stream>>>(inw, inwb, (4 * 2 * DI * DM) / 4);
  k_f2b<<<2048, 256, 0, stream>>>(ow,  owb,  (4 * DM * DI) / 4);
  k_f2b_pad<<<2048, 256, 0, stream>>>(emb, ebw, 1, VOC, VOCP, DM, DM);
  k_f2b_pad<<<1024, 256, 0, stream>>>(xw,  xwb, 4, 80, 128, DI, DI);
  k_f2b_pad<<<1024, 256, 0, stream>>>(dtw, dtwb, 4, DI, DI, DR, 64);

  k_embed<<<M, 256, 0, stream>>>(ids, times, emb, tw, tb, h);

  for (int i = 0; i < 4; i++) {
    k_rmsnorm<<<M, 256, 0, stream>>>(h, nw + i * DM, hnb);
    {  // x = hn @ in_proj_x^T ; z = hn @ in_proj_z^T   (bf16 out)
      dim3 g(M / 128, DI / 128);
      k_gemm_mfma<<<g, 256, 0, stream>>>(hnb, DM, inwb + (size_t)i * 2 * DI * DM, DM,
                                         nullptr, nullptr, xb, DI, DI, DM, 0, 0);
      k_gemm_mfma<<<g, 256, 0, stream>>>(hnb, DM,
                                         inwb + (size_t)i * 2 * DI * DM + (size_t)DI * DM, DM,
                                         nullptr, nullptr, zbuf, DI, DI, DM, 0, 0);
    }
    {  // xcb = silu(conv1d(x) + cb)   (vectorized, 8 d's per thread)
      int blocks = (int)(((size_t)M * DI / 8) / 256);
      k_conv8<<<blocks, 256, 0, stream>>>(xb, cw + i * DI * DC, cb + i * DI, xcb);
    }
    {  // xdbl = xc @ x_proj^T  (bf16 out, N=80, padded weights)
      dim3 g(M / 128, 1);
      k_gemm_mfma<<<g, 256, 0, stream>>>(xcb, DI, xwb + (size_t)i * 128 * DI, DI,
                                         nullptr, nullptr, xdblb, 80, 80, DI, 0, 0);
    }
    {  // delta = softplus(xdbl @ dtw_pad^T + dtb)  -> bf16
      dim3 g(M / 128, DI / 128);
      k_gemm_mfma<<<g, 256, 0, stream>>>(xdblb, 80, dtwb + (size_t)i * DI * 64, 64,
                                         dtb + i * DI, nullptr, dltb, DI, DI, 64, 1, 0);
    }
    {  // chunked selective scan + y*silu(z), in place over xcb
      dim3 g1(DI / 256, NC, Bc);
      k_scan1<<<g1, 256, 0, stream>>>(dltb, xcb, xdblb, alog + (size_t)i * DI * DS, scb);
      k_scan2<<<(Bc * DI * DS) / 256, 256, 0, stream>>>(scb);
      k_scan3<<<g1, 256, 0, stream>>>(dltb, zbuf, xcb, xdblb,
                                      alog + (size_t)i * DI * DS, dsk + i * DI, scb);
    }
    {  // h += y @ out_proj^T   (f32, resAdd)
      dim3 g(M / 128, DM / 128);
      k_gemm_mfma<<<g, 256, 0, stream>>>(xcb, DI, owb + (size_t)i * DM * DI, DI,
                                         nullptr, h, nullptr, DM, DM, DI, 0, 1);
    }
  }

  k_rmsnorm<<<M, 256, 0, stream>>>(h, nfw, hnb);
  {  // logits = hn @ embed^T   (N=1969, padded rows)
    dim3 g(M / 128, VOCP / 128);
    k_gemm_mfma<<<g, 256, 0, stream>>>(hnb, DM, ebw, DM,
                                       nullptr, out, nullptr, VOC, VOC, DM, 0, 0);
  }
}